// Round 11
// baseline (282.089 us; speedup 1.0000x reference)
//
#include <hip/hip_runtime.h>
#include <cstddef>

// Block-cooperative MFMA MixModel, 32 rows/tile (R11):
//   GEMM1 SWAPPED (R9/R10-verified): lane holds h[row=ln][4k] -> tanh -> cvt_pk -> b64.
//   GEMM2 SWAPPED (R9-verified op order) with 144-col padded internal layout:
//     internal col n = 8q+m: m<3 -> W2a[:,3q+m]; m==3 -> pad; m>=4 -> W2b[:,4q+m-4].
//     Lane (ln,lg) of tile g holds C2[row=ln][16g+4lg..+3] -> 2 cvt_pk + 1 ds_write_b64.
//     9 t-tiles split 3/2/2/2 across waves.
//   c2s bf16 [32][148]: slot = internal col; epilogue reads 2 b64 + shift/and unpack.
//   LDS 25344 B -> 6 blocks/CU, grid 1536.
//   tanh = clamped Pade(3,2) (1 transcendental; |err|<=0.024, threshold 0.6075 ok).
// u staging, h_sh layout/reads, epilogue structure: R8/R10-verified.

typedef __attribute__((ext_vector_type(8))) __bf16 bf16x8;
typedef __attribute__((ext_vector_type(8))) short short8;
typedef __attribute__((ext_vector_type(4))) float f32x4;

__device__ __forceinline__ unsigned short f2bf(float f) {
    // manual RNE float->bf16 (init-time only)
    unsigned int u = __float_as_uint(f);
    unsigned int r = (u + 0x7FFFu + ((u >> 16) & 1u)) >> 16;
    return (unsigned short)r;
}

__device__ __forceinline__ unsigned int cvt_pk_bf16(float lo, float hi) {
    // T12-documented gfx950 instruction: D = {lo16: bf16(S0), hi16: bf16(S1)}
    unsigned int r;
    asm("v_cvt_pk_bf16_f32 %0, %1, %2" : "=v"(r) : "v"(lo), "v"(hi));
    return r;
}

__device__ __forceinline__ float bf_lo(unsigned int u) {
    return __uint_as_float(u << 16);
}
__device__ __forceinline__ float bf_hi(unsigned int u) {
    return __uint_as_float(u & 0xFFFF0000u);
}

// --- mfma wrapper: tolerate either V8bf16 or V8i16 builtin signature ---
template <typename A>
__device__ __forceinline__ auto mfma_try(A a, A b, f32x4 c, int)
    -> decltype(__builtin_amdgcn_mfma_f32_16x16x32_bf16(a, b, c, 0, 0, 0)) {
    return __builtin_amdgcn_mfma_f32_16x16x32_bf16(a, b, c, 0, 0, 0);
}
template <typename A>
__device__ __forceinline__ f32x4 mfma_try(A a, A b, f32x4 c, long) {
    return __builtin_amdgcn_mfma_f32_16x16x32_bf16(
        __builtin_bit_cast(short8, a), __builtin_bit_cast(short8, b), c, 0, 0, 0);
}
__device__ __forceinline__ f32x4 mfma_bf16(short8 a, short8 b, f32x4 c) {
    return mfma_try(__builtin_bit_cast(bf16x8, a), __builtin_bit_cast(bf16x8, b), c, 0);
}

__device__ __forceinline__ float tanh_pade(float x) {
    // clamped Pade(3,2): t(27+t^2)/(27+9t^2); max err +0.024 @ |x|~1.5, saturates at 1
    const float t = fminf(fmaxf(x, -3.0f), 3.0f);
    const float s = t * t;
    return __fdividef(t * (27.0f + s), fmaf(9.0f, s, 27.0f));
}

__global__ __launch_bounds__(256, 6) void mixmodel_mfma11(
    const float* __restrict__ u,      // N*36
    const float* __restrict__ reg1,   // 6
    const float* __restrict__ reg2,   // 4
    const float* __restrict__ W1,     // 18*128
    const float* __restrict__ b1,     // 128
    const float* __restrict__ W2a,    // 128*54
    const float* __restrict__ b2a,    // 54
    const float* __restrict__ W2b,    // 128*72
    const float* __restrict__ b2b,    // 72
    float* __restrict__ out,          // N*36
    int N, int ntiles)
{
    __shared__ __align__(16) float          u_ext[32 * 40];   // 5120 B
    __shared__ __align__(16) unsigned short h_sh[32 * 136];   // 8704 B (verified layout)
    __shared__ __align__(16) unsigned short u_bf[32 * 32];    // 2048 B
    __shared__ __align__(16) unsigned short c2s[32 * 148];    // 9472 B bf16, slot = internal col
    // total = 25344 B -> 6 blocks/CU

    const int tid = threadIdx.x;
    const int wid = tid >> 6;
    const int l   = tid & 63;
    const int ln  = l & 15;
    const int lg  = l >> 4;
    const int nb  = wid * 32;   // GEMM1 column base (hidden dim), unchanged

    reinterpret_cast<unsigned int*>(u_bf)[tid]       = 0u;
    reinterpret_cast<unsigned int*>(u_bf)[tid + 256] = 0u;
    __syncthreads();

    // ---- GEMM1 weights (swapped; R10-verified): 2 t-tiles over this wave's 32 cols ----
    short8 b1f[2];
    f32x4 bias1v[2];
#pragma unroll
    for (int t = 0; t < 2; ++t) {
        const int n = nb + t * 16 + ln;
        short8 v;
#pragma unroll
        for (int j = 0; j < 8; ++j) {
            const int k = lg * 8 + j;
            const float w = (k < 18) ? W1[k * 128 + n] : 0.0f;
            v[j] = (short)f2bf(w);
        }
        b1f[t] = v;
        bias1v[t] = *reinterpret_cast<const f32x4*>(&b1[nb + t * 16 + lg * 4]);
    }

    // ---- GEMM2 weights (swapped, 144-col layout): tiles 3/2/2/2 per wave ----
    const int NT    = (wid == 0) ? 3 : 2;
    const int gbase = (wid == 0) ? 0 : 2 * wid + 1;  // {0,3,5,7}
    short8 b2f[3][4];
    f32x4 bias2v[3];
    int c2off[3];
#pragma unroll
    for (int tl = 0; tl < 3; ++tl) {
        if (tl < NT) {
            const int g  = gbase + tl;
            const int nf = 16 * g + ln;          // weight-fragment internal col
            const int q  = nf >> 3, m = nf & 7;
#pragma unroll
            for (int kk = 0; kk < 4; ++kk) {
                short8 w2;
#pragma unroll
                for (int j = 0; j < 8; ++j) {
                    const int k = kk * 32 + lg * 8 + j;
                    float w;
                    if (m < 3)       w = W2a[k * 54 + 3 * q + m];
                    else if (m == 3) w = 0.0f;
                    else             w = W2b[k * 72 + 4 * q + (m - 4)];
                    w2[j] = (short)f2bf(w);
                }
                b2f[tl][kk] = w2;
            }
            f32x4 bv;
#pragma unroll
            for (int r = 0; r < 4; ++r) {
                const int n  = 16 * g + 4 * lg + r;   // this lane's D-quad internal col
                const int qq = n >> 3, mm = n & 7;
                bv[r] = (mm < 3) ? b2a[3 * qq + mm]
                                 : (mm == 3 ? 0.0f : b2b[4 * qq + (mm - 4)]);
            }
            bias2v[tl] = bv;
            c2off[tl]  = 16 * g + 4 * lg;
        }
    }

    // ---- regression coefficients (wave-uniform -> SGPR) ----
    const float r10 = reg1[0], r11 = reg1[1], r12 = reg1[2];
    const float r13 = reg1[3], r14 = reg1[4], r15 = reg1[5];
    const float r20 = reg2[0], r21 = reg2[1], r22 = reg2[2], r23 = reg2[3];

    const float4* ug = reinterpret_cast<const float4*>(u);
    const long fmax4 = (long)N * 9 - 1;
    const int gs = gridDim.x;

    // ---- staging maps (R8-verified) ----
    const int row0 = tid / 9,          c0 = tid - row0 * 9;
    const int row1 = (256 + tid) / 9,  c1 = (256 + tid) - row1 * 9;
    const int hrow = (tid - 192) >> 1, hside = tid & 1;

    float4 pf0, pf1; float2 pfh;
    {
        const int r0 = blockIdx.x * 32;
        long g0 = (long)r0 * 9 + tid; if (g0 > fmax4) g0 = fmax4;
        pf0 = ug[g0];
        if (tid < 32) {
            long g1 = (long)r0 * 9 + 256 + tid; if (g1 > fmax4) g1 = fmax4;
            pf1 = ug[g1];
        }
        if (tid >= 192) {
            int rr = r0 + hrow; if (rr > N - 1) rr = N - 1;
            pfh = *reinterpret_cast<const float2*>(u + (size_t)rr * 36 + (hside ? 0 : 34));
        }
    }

    for (int tile = blockIdx.x; tile < ntiles; tile += gs) {
        // ---- stage u_ext / u_bf; prefetch next (R8-verified; cvt_pk for u_bf) ----
        {
            float* dst = &u_ext[row0 * 40 + 2 + c0 * 4];
            reinterpret_cast<float2*>(dst)[0] = make_float2(pf0.x, pf0.y);
            reinterpret_cast<float2*>(dst)[1] = make_float2(pf0.z, pf0.w);
            reinterpret_cast<unsigned int*>(u_bf)[row0 * 16 + c0] =
                cvt_pk_bf16(pf0.x, pf0.z);
            if (tid < 32) {
                float* dst1 = &u_ext[row1 * 40 + 2 + c1 * 4];
                reinterpret_cast<float2*>(dst1)[0] = make_float2(pf1.x, pf1.y);
                reinterpret_cast<float2*>(dst1)[1] = make_float2(pf1.z, pf1.w);
                reinterpret_cast<unsigned int*>(u_bf)[row1 * 16 + c1] =
                    cvt_pk_bf16(pf1.x, pf1.z);
            }
            if (tid >= 192)
                *reinterpret_cast<float2*>(&u_ext[hrow * 40 + (hside ? 38 : 0)]) = pfh;

            if (tile + gs < ntiles) {
                const int r0n = (tile + gs) * 32;
                long g0 = (long)r0n * 9 + tid; if (g0 > fmax4) g0 = fmax4;
                pf0 = ug[g0];
                if (tid < 32) {
                    long g1 = (long)r0n * 9 + 256 + tid; if (g1 > fmax4) g1 = fmax4;
                    pf1 = ug[g1];
                }
                if (tid >= 192) {
                    int rr = r0n + hrow; if (rr > N - 1) rr = N - 1;
                    pfh = *reinterpret_cast<const float2*>(u + (size_t)rr * 36 + (hside ? 0 : 34));
                }
            }
        }
        __syncthreads();  // bar1: u ready

        // ---- GEMM1 SWAPPED: tanh(Pade) + cvt_pk -> 1 ds_write_b64 per (rb,t) ----
#pragma unroll
        for (int rb = 0; rb < 2; ++rb) {
            const short8 a1 = *reinterpret_cast<const short8*>(
                &u_bf[(rb * 16 + ln) * 32 + lg * 8]);
#pragma unroll
            for (int t = 0; t < 2; ++t) {
                const f32x4 h4 = mfma_bf16(b1f[t], a1, bias1v[t]);   // SWAPPED -> h^T
                const unsigned int p0 =
                    cvt_pk_bf16(tanh_pade(h4[0]), tanh_pade(h4[1]));
                const unsigned int p1 =
                    cvt_pk_bf16(tanh_pade(h4[2]), tanh_pade(h4[3]));
                *reinterpret_cast<uint2*>(
                    &h_sh[(rb * 16 + ln) * 136 + nb + t * 16 + lg * 4]) =
                    make_uint2(p0, p1);
            }
        }
        __syncthreads();  // bar2: h ready

        // ---- GEMM2 SWAPPED (144 cols): b128 h reads (unchanged), MFMA, b64 c2 writes ----
        f32x4 acc2[2][3];
#pragma unroll
        for (int rb = 0; rb < 2; ++rb)
#pragma unroll
            for (int tl = 0; tl < 3; ++tl)
                if (tl < NT) acc2[rb][tl] = bias2v[tl];

#pragma unroll
        for (int rb = 0; rb < 2; ++rb) {
            const int arow = rb * 16 + ln;
#pragma unroll
            for (int kk = 0; kk < 4; ++kk) {
                const short8 a2 = *reinterpret_cast<const short8*>(
                    &h_sh[arow * 136 + kk * 32 + lg * 8]);
#pragma unroll
                for (int tl = 0; tl < 3; ++tl)
                    if (tl < NT)
                        acc2[rb][tl] = mfma_bf16(b2f[tl][kk], a2, acc2[rb][tl]);  // SWAPPED
            }
        }

#pragma unroll
        for (int rb = 0; rb < 2; ++rb) {
            const int rbase = (rb * 16 + ln) * 148;
#pragma unroll
            for (int tl = 0; tl < 3; ++tl) {
                if (tl < NT) {
                    const unsigned int lo = cvt_pk_bf16(acc2[rb][tl][0], acc2[rb][tl][1]);
                    const unsigned int hi = cvt_pk_bf16(acc2[rb][tl][2], acc2[rb][tl][3]);
                    *reinterpret_cast<uint2*>(&c2s[rbase + c2off[tl]]) =
                        make_uint2(lo, hi);
                }
            }
        }
        __syncthreads();  // bar3: c2 ready

        // ---- epilogue: u_ext b64 reads (unchanged) + c2 2x b64 bf16 reads ----
        const int r0 = tile * 32;
#pragma unroll
        for (int s = 0; s < 3; ++s) {
            const int w = s * 256 + tid;
            if (w < 576) {
                const int row = w / 18;
                const int i   = w - row * 18;
                const int rg  = r0 + row;

                const float2 v0 = *reinterpret_cast<const float2*>(&u_ext[row * 40 + 2 * i]);
                const float2 v1 = *reinterpret_cast<const float2*>(&u_ext[row * 40 + 2 * i + 2]);
                const float2 v2 = *reinterpret_cast<const float2*>(&u_ext[row * 40 + 2 * i + 4]);
                const uint2  q0 = *reinterpret_cast<const uint2*>(&c2s[row * 148 + 8 * i]);
                const uint2  q1 = *reinterpret_cast<const uint2*>(&c2s[row * 148 + 8 * i + 4]);

                const float um2 = v0.x, uA = v0.y;
                const float ue  = v1.x, uo = v1.y;
                const float up2 = v2.x, uC = v2.y;

                const float o00 = bf_lo(q0.x), o01 = bf_hi(q0.x), o02 = bf_lo(q0.y);
                const float o10 = bf_lo(q1.x), o11 = bf_hi(q1.x);
                const float o12 = bf_lo(q1.y), o13 = bf_hi(q1.y);

                const float oe = o00 + o01 * uA + o02 * uo;
                const float oo = o10 + o11 * uA + o12 * uo + o13 * uC;

                float re = r10;
                re = fmaf(r11, ue,       re);
                re = fmaf(r12, uo,       re);
                re = fmaf(r13, um2 * uA, re);
                re = fmaf(r14, uA * up2, re);
                re = fmaf(r15, ue * uo,  re);

                float ro = r20;
                ro = fmaf(r21, uo,       ro);
                ro = fmaf(r22, uA * ue,  ro);
                ro = fmaf(r23, ue * up2, ro);

                if (rg < N)
                    *reinterpret_cast<float2*>(out + (size_t)rg * 36 + 2 * i) =
                        make_float2(oe + re, oo + ro);
            }
        }
        __syncthreads();  // bar4: buffers free for next staging
    }
}

extern "C" void kernel_launch(void* const* d_in, const int* in_sizes, int n_in,
                              void* d_out, int out_size, void* d_ws, size_t ws_size,
                              hipStream_t stream) {
    // d_in order: t, u, reg1, reg2, W1, b1, W2a, b2a, W2b, b2b
    const float* u    = (const float*)d_in[1];
    const float* reg1 = (const float*)d_in[2];
    const float* reg2 = (const float*)d_in[3];
    const float* W1   = (const float*)d_in[4];
    const float* b1   = (const float*)d_in[5];
    const float* W2a  = (const float*)d_in[6];
    const float* b2a  = (const float*)d_in[7];
    const float* W2b  = (const float*)d_in[8];
    const float* b2b  = (const float*)d_in[9];
    float* out = (float*)d_out;

    const int N = in_sizes[1] / 36;
    const int ntiles = (N + 31) / 32;
    int grid = ntiles < 1536 ? ntiles : 1536;   // 6 blocks/CU
    if (grid < 1) grid = 1;
    mixmodel_mfma11<<<grid, 256, 0, stream>>>(u, reg1, reg2, W1, b1,
                                              W2a, b2a, W2b, b2b, out, N, ntiles);
}

// Round 13
// 75.465 us; speedup vs baseline: 3.7380x; 3.7380x over previous
//
#include <hip/hip_runtime.h>
#include <cstddef>

// Block-cooperative MFMA MixModel, 32 rows/tile (R13 = R10 verbatim + three
// R11-verified substitutions; zero new addressing):
//   GEMM1 SWAPPED: lane holds h[row=ln][4k] -> tanh_pade -> cvt_pk -> ds_write_b64.
//   GEMM2 UNSWAPPED: h_sh [row][k] b128 reads, 16 MFMA, scalar FLOAT c2 writes
//     (R10-verified; R12's scalar-bf16 write quartet NaN'd -> banned).
//   c2s float [32][148] quad-interleaved, epilogue 2x f32x4 reads (R10-verified).
//   Subs vs R10 (each verified in identical context in R11):
//     1. tanh = clamped Pade(3,2)   2. h-pack via v_cvt_pk_bf16_f32
//     3. u_bf staging via v_cvt_pk_bf16_f32

typedef __attribute__((ext_vector_type(8))) __bf16 bf16x8;
typedef __attribute__((ext_vector_type(8))) short short8;
typedef __attribute__((ext_vector_type(4))) float f32x4;

__device__ __forceinline__ unsigned short f2bf(float f) {
    // manual RNE float->bf16 (init-time only)
    unsigned int u = __float_as_uint(f);
    unsigned int r = (u + 0x7FFFu + ((u >> 16) & 1u)) >> 16;
    return (unsigned short)r;
}

__device__ __forceinline__ unsigned int cvt_pk_bf16(float lo, float hi) {
    // gfx950 packed convert (R11-verified): D = {lo16: bf16(S0), hi16: bf16(S1)}
    unsigned int r;
    asm("v_cvt_pk_bf16_f32 %0, %1, %2" : "=v"(r) : "v"(lo), "v"(hi));
    return r;
}

// --- mfma wrapper: tolerate either V8bf16 or V8i16 builtin signature ---
template <typename A>
__device__ __forceinline__ auto mfma_try(A a, A b, f32x4 c, int)
    -> decltype(__builtin_amdgcn_mfma_f32_16x16x32_bf16(a, b, c, 0, 0, 0)) {
    return __builtin_amdgcn_mfma_f32_16x16x32_bf16(a, b, c, 0, 0, 0);
}
template <typename A>
__device__ __forceinline__ f32x4 mfma_try(A a, A b, f32x4 c, long) {
    return __builtin_amdgcn_mfma_f32_16x16x32_bf16(
        __builtin_bit_cast(short8, a), __builtin_bit_cast(short8, b), c, 0, 0, 0);
}
__device__ __forceinline__ f32x4 mfma_bf16(short8 a, short8 b, f32x4 c) {
    return mfma_try(__builtin_bit_cast(bf16x8, a), __builtin_bit_cast(bf16x8, b), c, 0);
}

__device__ __forceinline__ float tanh_pade(float x) {
    // clamped Pade(3,2) (R11-verified): t(27+t^2)/(27+9t^2), |err|<=0.024
    const float t = fminf(fmaxf(x, -3.0f), 3.0f);
    const float s = t * t;
    return __fdividef(t * (27.0f + s), fmaf(9.0f, s, 27.0f));
}

__global__ __launch_bounds__(256, 4) void mixmodel_mfma13(
    const float* __restrict__ u,      // N*36
    const float* __restrict__ reg1,   // 6
    const float* __restrict__ reg2,   // 4
    const float* __restrict__ W1,     // 18*128
    const float* __restrict__ b1,     // 128
    const float* __restrict__ W2a,    // 128*54
    const float* __restrict__ b2a,    // 54
    const float* __restrict__ W2b,    // 128*72
    const float* __restrict__ b2b,    // 72
    float* __restrict__ out,          // N*36
    int N, int ntiles)
{
    __shared__ __align__(16) float          u_ext[32 * 40];   // 5120 B
    __shared__ __align__(16) unsigned short h_sh[32 * 136];   // 8704 B (verified layout)
    __shared__ __align__(16) unsigned short u_bf[32 * 32];    // 2048 B
    __shared__ __align__(16) float          c2s[32 * 148];    // 18944 B float, [row][8i+slot]
    // total = 34816 B -> 4 blocks/CU

    const int tid = threadIdx.x;
    const int wid = tid >> 6;
    const int l   = tid & 63;
    const int ln  = l & 15;
    const int lg  = l >> 4;
    const int nb  = wid * 32;

    reinterpret_cast<unsigned int*>(u_bf)[tid]       = 0u;
    reinterpret_cast<unsigned int*>(u_bf)[tid + 256] = 0u;
    __syncthreads();

    // ---- resident weight fragments (R10-verified data + maps): 40 VGPRs ----
    short8 b1f[2];
    short8 b2f[2][4];
    f32x4 bias1v[2];            // per-reg bias for swapped GEMM1
    float bias2[2];             // per-lane bias for unswapped GEMM2
    int c2idx[2];               // quad-interleaved in-row index (max 143)
#pragma unroll
    for (int t = 0; t < 2; ++t) {
        const int n = nb + t * 16 + ln;
        short8 v;
#pragma unroll
        for (int j = 0; j < 8; ++j) {
            const int k = lg * 8 + j;
            const float w = (k < 18) ? W1[k * 128 + n] : 0.0f;
            v[j] = (short)f2bf(w);
        }
        b1f[t] = v;
        bias1v[t] = *reinterpret_cast<const f32x4*>(&b1[nb + t * 16 + lg * 4]);
        bias2[t] = (n < 54) ? b2a[n] : (n < 126 ? b2b[n - 54] : 0.0f);
        if (n < 54)       c2idx[t] = (n / 3) * 8 + (n % 3);
        else if (n < 126) { const int m = n - 54; c2idx[t] = (m >> 2) * 8 + 4 + (m & 3); }
        else              c2idx[t] = 3;  // dump slot, never read
#pragma unroll
        for (int kk = 0; kk < 4; ++kk) {
            short8 w2;
#pragma unroll
            for (int j = 0; j < 8; ++j) {
                const int k = kk * 32 + lg * 8 + j;
                float w;
                if (n < 54)       w = W2a[k * 54 + n];
                else if (n < 126) w = W2b[k * 72 + (n - 54)];
                else              w = 0.0f;
                w2[j] = (short)f2bf(w);
            }
            b2f[t][kk] = w2;
        }
    }

    // ---- regression coefficients (wave-uniform -> SGPR) ----
    const float r10 = reg1[0], r11 = reg1[1], r12 = reg1[2];
    const float r13 = reg1[3], r14 = reg1[4], r15 = reg1[5];
    const float r20 = reg2[0], r21 = reg2[1], r22 = reg2[2], r23 = reg2[3];

    const float4* ug = reinterpret_cast<const float4*>(u);
    const long fmax4 = (long)N * 9 - 1;
    const int gs = gridDim.x;

    // ---- staging maps (R8-verified) ----
    const int row0 = tid / 9,          c0 = tid - row0 * 9;
    const int row1 = (256 + tid) / 9,  c1 = (256 + tid) - row1 * 9;
    const int hrow = (tid - 192) >> 1, hside = tid & 1;

    float4 pf0, pf1; float2 pfh;
    {
        const int r0 = blockIdx.x * 32;
        long g0 = (long)r0 * 9 + tid; if (g0 > fmax4) g0 = fmax4;
        pf0 = ug[g0];
        if (tid < 32) {
            long g1 = (long)r0 * 9 + 256 + tid; if (g1 > fmax4) g1 = fmax4;
            pf1 = ug[g1];
        }
        if (tid >= 192) {
            int rr = r0 + hrow; if (rr > N - 1) rr = N - 1;
            pfh = *reinterpret_cast<const float2*>(u + (size_t)rr * 36 + (hside ? 0 : 34));
        }
    }

    for (int tile = blockIdx.x; tile < ntiles; tile += gs) {
        // ---- stage u_ext / u_bf (cvt_pk, R11-verified); prefetch next ----
        {
            float* dst = &u_ext[row0 * 40 + 2 + c0 * 4];
            reinterpret_cast<float2*>(dst)[0] = make_float2(pf0.x, pf0.y);
            reinterpret_cast<float2*>(dst)[1] = make_float2(pf0.z, pf0.w);
            reinterpret_cast<unsigned int*>(u_bf)[row0 * 16 + c0] =
                cvt_pk_bf16(pf0.x, pf0.z);
            if (tid < 32) {
                float* dst1 = &u_ext[row1 * 40 + 2 + c1 * 4];
                reinterpret_cast<float2*>(dst1)[0] = make_float2(pf1.x, pf1.y);
                reinterpret_cast<float2*>(dst1)[1] = make_float2(pf1.z, pf1.w);
                reinterpret_cast<unsigned int*>(u_bf)[row1 * 16 + c1] =
                    cvt_pk_bf16(pf1.x, pf1.z);
            }
            if (tid >= 192)
                *reinterpret_cast<float2*>(&u_ext[hrow * 40 + (hside ? 38 : 0)]) = pfh;

            if (tile + gs < ntiles) {
                const int r0n = (tile + gs) * 32;
                long g0 = (long)r0n * 9 + tid; if (g0 > fmax4) g0 = fmax4;
                pf0 = ug[g0];
                if (tid < 32) {
                    long g1 = (long)r0n * 9 + 256 + tid; if (g1 > fmax4) g1 = fmax4;
                    pf1 = ug[g1];
                }
                if (tid >= 192) {
                    int rr = r0n + hrow; if (rr > N - 1) rr = N - 1;
                    pfh = *reinterpret_cast<const float2*>(u + (size_t)rr * 36 + (hside ? 0 : 34));
                }
            }
        }
        __syncthreads();  // bar1: u ready

        // ---- GEMM1 SWAPPED: tanh_pade + cvt_pk -> 1 ds_write_b64 per (rb,t) ----
#pragma unroll
        for (int rb = 0; rb < 2; ++rb) {
            const short8 a1 = *reinterpret_cast<const short8*>(
                &u_bf[(rb * 16 + ln) * 32 + lg * 8]);
#pragma unroll
            for (int t = 0; t < 2; ++t) {
                const f32x4 h4 = mfma_bf16(b1f[t], a1, bias1v[t]);   // SWAPPED -> h^T
                const unsigned int p0 =
                    cvt_pk_bf16(tanh_pade(h4[0]), tanh_pade(h4[1]));
                const unsigned int p1 =
                    cvt_pk_bf16(tanh_pade(h4[2]), tanh_pade(h4[3]));
                *reinterpret_cast<uint2*>(
                    &h_sh[(rb * 16 + ln) * 136 + nb + t * 16 + lg * 4]) =
                    make_uint2(p0, p1);
            }
        }
        __syncthreads();  // bar2: h ready

        // ---- GEMM2 UNSWAPPED (R10-verified): b128 reads, 16 MFMA ----
        f32x4 acc2[2][2];
#pragma unroll
        for (int rb = 0; rb < 2; ++rb)
#pragma unroll
            for (int t = 0; t < 2; ++t) acc2[rb][t] = (f32x4)bias2[t];

#pragma unroll
        for (int rb = 0; rb < 2; ++rb) {
            const int arow = rb * 16 + ln;
#pragma unroll
            for (int kk = 0; kk < 4; ++kk) {
                const short8 a2 = *reinterpret_cast<const short8*>(
                    &h_sh[arow * 136 + kk * 32 + lg * 8]);
#pragma unroll
                for (int t = 0; t < 2; ++t)
                    acc2[rb][t] = mfma_bf16(a2, b2f[t][kk], acc2[rb][t]);
            }
        }

        // ---- C2 -> LDS float (R10-verified addressing, stride 148) ----
#pragma unroll
        for (int rb = 0; rb < 2; ++rb)
#pragma unroll
            for (int t = 0; t < 2; ++t)
#pragma unroll
                for (int r = 0; r < 4; ++r)
                    c2s[(rb * 16 + lg * 4 + r) * 148 + c2idx[t]] = acc2[rb][t][r];
        __syncthreads();  // bar3: c2 ready

        // ---- epilogue (R10-verified, stride 148) ----
        const int r0 = tile * 32;
#pragma unroll
        for (int s = 0; s < 3; ++s) {
            const int w = s * 256 + tid;
            if (w < 576) {
                const int row = w / 18;
                const int i   = w - row * 18;
                const int rg  = r0 + row;

                const float2 v0 = *reinterpret_cast<const float2*>(&u_ext[row * 40 + 2 * i]);
                const float2 v1 = *reinterpret_cast<const float2*>(&u_ext[row * 40 + 2 * i + 2]);
                const float2 v2 = *reinterpret_cast<const float2*>(&u_ext[row * 40 + 2 * i + 4]);
                const f32x4  q0 = *reinterpret_cast<const f32x4*>(&c2s[row * 148 + 8 * i]);
                const f32x4  q1 = *reinterpret_cast<const f32x4*>(&c2s[row * 148 + 8 * i + 4]);

                const float um2 = v0.x, uA = v0.y;
                const float ue  = v1.x, uo = v1.y;
                const float up2 = v2.x, uC = v2.y;

                const float oe = q0[0] + q0[1] * uA + q0[2] * uo;
                const float oo = q1[0] + q1[1] * uA + q1[2] * uo + q1[3] * uC;

                float re = r10;
                re = fmaf(r11, ue,       re);
                re = fmaf(r12, uo,       re);
                re = fmaf(r13, um2 * uA, re);
                re = fmaf(r14, uA * up2, re);
                re = fmaf(r15, ue * uo,  re);

                float ro = r20;
                ro = fmaf(r21, uo,       ro);
                ro = fmaf(r22, uA * ue,  ro);
                ro = fmaf(r23, ue * up2, ro);

                if (rg < N)
                    *reinterpret_cast<float2*>(out + (size_t)rg * 36 + 2 * i) =
                        make_float2(oe + re, oo + ro);
            }
        }
        __syncthreads();  // bar4: buffers free for next staging
    }
}

extern "C" void kernel_launch(void* const* d_in, const int* in_sizes, int n_in,
                              void* d_out, int out_size, void* d_ws, size_t ws_size,
                              hipStream_t stream) {
    // d_in order: t, u, reg1, reg2, W1, b1, W2a, b2a, W2b, b2b
    const float* u    = (const float*)d_in[1];
    const float* reg1 = (const float*)d_in[2];
    const float* reg2 = (const float*)d_in[3];
    const float* W1   = (const float*)d_in[4];
    const float* b1   = (const float*)d_in[5];
    const float* W2a  = (const float*)d_in[6];
    const float* b2a  = (const float*)d_in[7];
    const float* W2b  = (const float*)d_in[8];
    const float* b2b  = (const float*)d_in[9];
    float* out = (float*)d_out;

    const int N = in_sizes[1] / 36;
    const int ntiles = (N + 31) / 32;
    int grid = ntiles < 1024 ? ntiles : 1024;
    if (grid < 1) grid = 1;
    mixmodel_mfma13<<<grid, 256, 0, stream>>>(u, reg1, reg2, W1, b1,
                                              W2a, b2a, W2b, b2b, out, N, ntiles);
}